// Round 8
// baseline (109.337 us; speedup 1.0000x reference)
//
#include <hip/hip_runtime.h>
#include <math.h>

// NoisyEmbedding: argmax_j( cos_sim(w[ids[i]], w[j]) + 20*gumbel[i][j] ) -> gather w[argmax]
//
// sims span <= 2 => only j with gumbel g within 0.1 of the ROW max can win
// (20*0.1 = 2). g = -log(-log u) monotone in u => all max/threshold work in
// the u-domain (zero transcendentals in the stream).
//
// ONE kernel, ONE block per row (BT = 2048 = 256 CUs x 8 blocks/CU => all
// blocks co-resident, perfectly equal work, no dispatch-round drain, and the
// row max + candidates are block-LOCAL: no second kernel, no workspace, no
// global atomics — the round-5 coherence trap is structurally impossible).
// Row bases are 4B-aligned only (V odd): boundary float4s are read by both
// neighboring blocks; out-of-row elements masked to -1.
// Two-level filter, all in u-domain with 0.1001 margin (0.0001 covers float
// slop of the power map; winner needs only 0.1):
//   per 8192-elem register-resident sub-chunk: keep u >= u_chunkmax^e^0.1001
//   epilogue: row max = max of 7 chunk maxima; re-filter to
//             u >= u_rowmax^e^0.1001 (~1.1 survive); exact f32 rescore
//             (norms on the fly); argmax (score desc, idx asc) = jnp.argmax.

constexpr int V  = 50257;
constexpr int D  = 768;
constexpr int BT = 2048;
constexpr int F4PT  = 8;                 // f32x4 per thread per sub-chunk
constexpr int SUBF4 = 256 * F4PT;        // 2048 f32x4 per sub-chunk
constexpr int NSUB  = 7;                 // 7*2048 >= 12565 f32x4 per row
constexpr int CCAPT = 160;               // LDS candidate cap (E ~ 7.7/row)
constexpr int RCAP  = 64;                // row-filtered cap (E ~ 1.13)
constexpr float KPOW = 1.1052847f;       // expf(0.1001)
constexpr float TWO_OVER_EPS = 20.0f;

typedef float f32x4 __attribute__((ext_vector_type(4)));

__global__ __launch_bounds__(256, 8) void k_all(
    const float* __restrict__ gum, const float* __restrict__ w,
    const int* __restrict__ ids, float* __restrict__ out) {
  __shared__ float s_red[4];
  __shared__ float s_cmax[NSUB];
  __shared__ float s_thr;
  __shared__ int   s_cnt;
  __shared__ float clu[CCAPT];
  __shared__ int   cli[CCAPT];
  __shared__ __align__(16) float q[D];
  __shared__ float lu[RCAP], lsc[RCAP];
  __shared__ int   li[RCAP];
  __shared__ float s_ut, s_invq;
  __shared__ int   s_n, s_sel;

  int tid = threadIdx.x, r = blockIdx.x;
  int lane = tid & 63, wid = tid >> 6;
  int lo = r * V, hi = lo + V;             // this block's row, flat elements
  int f4lo = lo >> 2, f4hi = (hi - 1) >> 2;

  if (tid == 0) s_cnt = 0;
  const f32x4* g4 = reinterpret_cast<const f32x4*>(gum);

  // ---- stream the row: 7 register-resident sub-chunks, two passes each ----
  for (int s = 0; s < NSUB; ++s) {
    int cbase = f4lo + s * SUBF4;
    f32x4 v[F4PT];
#pragma unroll
    for (int k = 0; k < F4PT; ++k) {
      int fi = cbase + k * 256 + tid;
      if (fi <= f4hi) v[k] = __builtin_nontemporal_load(&g4[fi]);
      else            v[k] = (f32x4){-1.f, -1.f, -1.f, -1.f};
    }
    float m = -1.f;
#pragma unroll
    for (int k = 0; k < F4PT; ++k) {
      int e0 = (cbase + k * 256 + tid) << 2;
#pragma unroll
      for (int j = 0; j < 4; ++j) {
        int idx = e0 + j;
        float uu = (idx >= lo && idx < hi) ? v[k][j] : -1.f;
        v[k][j] = uu;                      // mask boundary-vector strays
        m = fmaxf(m, uu);
      }
    }
#pragma unroll
    for (int off = 1; off < 64; off <<= 1)
      m = fmaxf(m, __shfl_xor(m, off, 64));
    if (lane == 0) s_red[wid] = m;
    __syncthreads();                       // also orders prev chunk's s_thr use
    if (tid == 0) {
      float cm = fmaxf(fmaxf(s_red[0], s_red[1]), fmaxf(s_red[2], s_red[3]));
      s_cmax[s] = cm;
      // g >= g_cmax - 0.1001 <=> u >= u_cmax^KPOW (u in (0,1]).
      // Empty chunk: cm = -1 -> NaN threshold -> all compares false.
      s_thr = expf(KPOW * logf(cm));
    }
    __syncthreads();
    float thr = s_thr;
#pragma unroll
    for (int k = 0; k < F4PT; ++k) {
      int e0 = (cbase + k * 256 + tid) << 2;
#pragma unroll
      for (int j = 0; j < 4; ++j) {
        float uu = v[k][j];
        if (uu >= thr) {                   // masked/-1 never pass
          int p = atomicAdd(&s_cnt, 1);    // LDS atomic, ~1.1 hits/chunk
          if (p < CCAPT) { cli[p] = e0 + j - lo; clu[p] = uu; }
        }
      }
    }
  }
  __syncthreads();

  // ---- epilogue: row threshold, q staging, re-filter ----
  int qid = ids[r];
  float qs = 0.f;
#pragma unroll
  for (int k = 0; k < 3; ++k) {
    float x = w[(size_t)qid * D + k * 256 + tid];
    q[k * 256 + tid] = x;
    qs += x * x;
  }
#pragma unroll
  for (int off = 32; off > 0; off >>= 1) qs += __shfl_down(qs, off, 64);
  if (lane == 0) s_red[wid] = qs;
  if (tid == 0) s_n = 0;
  __syncthreads();
  if (tid == 0) {
    float rm = -1.f;
    for (int s2 = 0; s2 < NSUB; ++s2) rm = fmaxf(rm, s_cmax[s2]);
    s_ut = expf(KPOW * logf(rm));          // row-level u threshold
    s_invq = 1.0f / fmaxf(sqrtf(s_red[0] + s_red[1] + s_red[2] + s_red[3]), 1e-12f);
  }
  __syncthreads();
  float ut = s_ut, invq = s_invq;
  int nc = s_cnt; if (nc > CCAPT) nc = CCAPT;
  for (int k2 = tid; k2 < nc; k2 += 256) {
    float uu = clu[k2];
    if (uu >= ut) {                        // ~1.13 survivors per row
      int p = atomicAdd(&s_n, 1);          // LDS atomic
      if (p < RCAP) { li[p] = cli[k2]; lu[p] = uu; }
    }
  }
  __syncthreads();
  int n = s_n; if (n > RCAP) n = RCAP;

  // ---- exact f32 rescore: one wave per candidate ----
  for (int cI = wid; cI < n; cI += 4) {
    int j = li[cI];
    const float4* p  = reinterpret_cast<const float4*>(w + (size_t)j * D);
    const float4* qp = reinterpret_cast<const float4*>(q);
    float dot = 0.f, n2 = 0.f;
#pragma unroll
    for (int k = 0; k < 3; ++k) {
      float4 a = p[k * 64 + lane];
      float4 b = qp[k * 64 + lane];
      dot += a.x * b.x + a.y * b.y + a.z * b.z + a.w * b.w;
      n2  += a.x * a.x + a.y * a.y + a.z * a.z + a.w * a.w;
    }
#pragma unroll
    for (int off = 32; off > 0; off >>= 1) {
      dot += __shfl_down(dot, off, 64);
      n2  += __shfl_down(n2,  off, 64);
    }
    if (lane == 0) {
      float invj = 1.0f / fmaxf(sqrtf(n2), 1e-12f);
      lsc[cI] = invq * invj * dot + TWO_OVER_EPS * (-logf(-logf(lu[cI])));
    }
  }
  __syncthreads();

  if (wid == 0) {                          // argmax: (score desc, idx asc)
    float bs = -INFINITY;
    int bj = 0x7fffffff;
    for (int cI = lane; cI < n; cI += 64) {
      float sv = lsc[cI];
      int j = li[cI];
      if (sv > bs || (sv == bs && j < bj)) { bs = sv; bj = j; }
    }
#pragma unroll
    for (int off = 32; off > 0; off >>= 1) {
      float os = __shfl_down(bs, off, 64);
      int   oj = __shfl_down(bj, off, 64);
      if (os > bs || (os == bs && oj < bj)) { bs = os; bj = oj; }
    }
    if (lane == 0) s_sel = bj;
  }
  __syncthreads();

  int sel = s_sel;
#pragma unroll
  for (int k = 0; k < 3; ++k)
    out[(size_t)r * D + k * 256 + tid] = w[(size_t)sel * D + k * 256 + tid];
}

extern "C" void kernel_launch(void* const* d_in, const int* in_sizes, int n_in,
                              void* d_out, int out_size, void* d_ws, size_t ws_size,
                              hipStream_t stream) {
  const int*   ids = (const int*)d_in[0];    // input_ids (B*T)
  const float* w   = (const float*)d_in[1];  // weight (V*D)
  const float* gum = (const float*)d_in[2];  // gumbel_u (BT*V)
  float* out = (float*)d_out;

  k_all<<<BT, 256, 0, stream>>>(gum, w, ids, out);   // no ws, no memset
}

// Round 9
// 78.283 us; speedup vs baseline: 1.3967x; 1.3967x over previous
//
#include <hip/hip_runtime.h>
#include <math.h>

// NoisyEmbedding: argmax_j( cos_sim(w[ids[i]], w[j]) + 20*gumbel[i][j] ) -> gather w[argmax]
//
// sims span <= 2 => only j with gumbel g within 0.1 of the ROW max can win
// (20*0.1 = 2). g = -log(-log u) monotone in u => all max/threshold work in
// the u-domain (no transcendentals in the stream). Two-level filter:
//   scan: per 2048-elem wave-chunk, keep survivors within 0.105 of the chunk-
//         segment max + store segment maxima. TOTAL = 2048*50257 => exactly
//         50257 full wave-chunks (no tail). Wave-independent: no barriers,
//         no LDS, no atomics (prefix-sum compaction via shfl_up).
//   score: rebuild ROW max from <=26 chunk maxima, re-filter candidates to
//         within 0.12 of the ROW max (~1.13/row), exact f32 rescore, argmax
//         with first-index tie-break (matches jnp.argmax), gather.
// Margins: needed gap <= 2/20 = 0.1; 0.105/0.12 minus ~0.01 u-domain float
// slop still > 0.1 => deterministic superset. Round-5 lesson: nothing crosses
// blocks except through the kernel boundary (no global atomics anywhere).

constexpr int V  = 50257;
constexpr int D  = 768;
constexpr int BT = 2048;
constexpr long TOTAL = (long)BT * V;            // 102,926,336 (fits int32)
constexpr int ITOTAL = (int)TOTAL;
constexpr int LOG2C  = 11;
constexpr int WCHUNK = 1 << LOG2C;              // 2048 elems per wave-chunk
constexpr int NWC    = ITOTAL / WCHUNK;         // = V = 50257 exactly, no tail
constexpr int CCAP   = 8;                       // per-chunk survivor cap (E~1.11)
constexpr int RCAP   = 64;                      // per-row candidate cap (E~1.13)
constexpr float KPOW_SCAN = 1.1107096f;         // expf(0.105)
constexpr float KPOW_ROW  = 1.1274969f;         // expf(0.12)
constexpr float TWO_OVER_EPS = 20.0f;

typedef float f32x4 __attribute__((ext_vector_type(4)));

// --- K1: per-wave scan: 8 x f32x4 per lane, butterfly segment maxima,
//         prefix-sum compacted survivor stores. No LDS, no barriers. ---
__global__ __launch_bounds__(256) void k_scan(const float* __restrict__ gum,
                                              int* __restrict__ ccnt,
                                              int* __restrict__ cflat,
                                              float* __restrict__ cuv,
                                              float* __restrict__ cmaxlo,
                                              float* __restrict__ cmaxhi) {
  int tid  = threadIdx.x;
  int lane = tid & 63;
  int wc   = blockIdx.x * 4 + (tid >> 6);
  if (wc >= NWC) return;                        // wave-uniform exit (tail block)

  int start  = wc << LOG2C;
  int row0   = start / V;                       // compile-time magic-div
  int bnd    = (row0 + 1) * V;                  // <=1 row boundary per chunk
  int f4base = start >> 2;

  const f32x4* g4 = reinterpret_cast<const f32x4*>(gum);
  f32x4 v[8];
#pragma unroll
  for (int k = 0; k < 8; ++k)                   // full coverage: no masking
    v[k] = __builtin_nontemporal_load(&g4[f4base + k * 64 + lane]);

  float mlo = -1.f, mhi = -1.f;                 // segment maxima (u in (0,1))
#pragma unroll
  for (int k = 0; k < 8; ++k) {
    int e0 = (f4base + k * 64 + lane) << 2;
#pragma unroll
    for (int j = 0; j < 4; ++j) {
      if (e0 + j < bnd) mlo = fmaxf(mlo, v[k][j]);
      else              mhi = fmaxf(mhi, v[k][j]);
    }
  }
#pragma unroll
  for (int off = 1; off < 64; off <<= 1) {      // butterfly: all lanes get max
    mlo = fmaxf(mlo, __shfl_xor(mlo, off, 64));
    mhi = fmaxf(mhi, __shfl_xor(mhi, off, 64));
  }
  if (lane == 0) { cmaxlo[wc] = mlo; cmaxhi[wc] = mhi; }  // written every call
  // g >= g_segmax - 0.105  <=>  u >= u_segmax^KPOW_SCAN (u in (0,1]).
  // Empty hi segment: mhi = -1 -> NaN threshold -> compares false (unused).
  float tlo = expf(KPOW_SCAN * logf(mlo));
  float thi = expf(KPOW_SCAN * logf(mhi));

  unsigned pm = 0;                              // 32 predicate bits per lane
#pragma unroll
  for (int k = 0; k < 8; ++k) {
    int e0 = (f4base + k * 64 + lane) << 2;
#pragma unroll
    for (int j = 0; j < 4; ++j) {
      int idx = e0 + j;
      if (v[k][j] >= ((idx < bnd) ? tlo : thi)) pm |= 1u << (k * 4 + j);
    }
  }
  int myc = __popc(pm);
  int incl = myc;                               // wave inclusive prefix sum
#pragma unroll
  for (int off = 1; off < 64; off <<= 1) {
    int t = __shfl_up(incl, off, 64);
    if (lane >= off) incl += t;
  }
  if (lane == 63) ccnt[wc] = (incl < CCAP) ? incl : CCAP;  // total, every call
  int p = incl - myc;                           // exclusive offset
  if (pm) {                                     // rare (~1.1 survivors/chunk)
#pragma unroll
    for (int k = 0; k < 8; ++k)
#pragma unroll
      for (int j = 0; j < 4; ++j)
        if ((pm >> (k * 4 + j)) & 1) {
          if (p < CCAP) {
            int idx = ((f4base + k * 64 + lane) << 2) + j;
            cflat[wc * CCAP + p] = idx;
            cuv[wc * CCAP + p]   = v[k][j];
          }
          ++p;
        }
  }
}

// --- K2: per row, rebuild row max from chunk maxima, row-filter candidates
//         (~1.13 survive), exact f32 rescore + argmax + gather. ---
__global__ __launch_bounds__(256) void k_score(const float* __restrict__ w,
                                               const int* __restrict__ ids,
                                               const int* __restrict__ ccnt,
                                               const int* __restrict__ cflat,
                                               const float* __restrict__ cuv,
                                               const float* __restrict__ cmaxlo,
                                               const float* __restrict__ cmaxhi,
                                               float* __restrict__ out) {
  __shared__ __align__(16) float q[D];
  __shared__ float lu[RCAP], lsc[RCAP];
  __shared__ int   li[RCAP];
  __shared__ float s_rm[32], s_red[4];
  __shared__ float s_ut, s_invq;
  __shared__ int   s_n, s_sel;
  int row = blockIdx.x;
  int tid = threadIdx.x;
  int lane = tid & 63, wid = tid >> 6;

  int c0 = (row * V) >> LOG2C;
  int c1 = (((row + 1) * V) - 1) >> LOG2C;
  int nch = c1 - c0 + 1;                        // <= 26
  if (tid == 0) s_n = 0;
  if (tid < nch) {
    int c = c0 + tid;
    int row0c = (c << LOG2C) / V;               // magic-div
    s_rm[tid] = (row0c == row) ? cmaxlo[c] : cmaxhi[c];
  }
  // stage q + norm partials (disjoint LDS, overlaps the tiny max loads)
  int qid = ids[row];
  float qs = 0.f;
#pragma unroll
  for (int k = 0; k < 3; ++k) {
    float x = w[(size_t)qid * D + k * 256 + tid];
    q[k * 256 + tid] = x;
    qs += x * x;
  }
#pragma unroll
  for (int off = 32; off > 0; off >>= 1) qs += __shfl_down(qs, off, 64);
  if (lane == 0) s_red[wid] = qs;
  __syncthreads();
  if (tid == 0) {
    float rm = -1.f;
    for (int k = 0; k < nch; ++k) rm = fmaxf(rm, s_rm[k]);
    // row-level: g >= g_rowmax - 0.12  <=>  u >= u_rowmax^KPOW_ROW
    s_ut = expf(KPOW_ROW * logf(rm));
    s_invq = 1.0f / fmaxf(sqrtf(s_red[0] + s_red[1] + s_red[2] + s_red[3]), 1e-12f);
  }
  __syncthreads();
  float ut = s_ut, invq = s_invq;

  if (tid < nch) {                              // collect + row-filter
    int c = c0 + tid;
    int m = ccnt[c]; if (m > CCAP) m = CCAP;
    int lo = row * V, hi = lo + V;
    for (int k = 0; k < m; ++k) {
      int fx = cflat[c * CCAP + k];
      float uu = cuv[c * CCAP + k];
      if (fx >= lo && fx < hi && uu >= ut) {    // ~1.13 survivors per row
        int p = atomicAdd(&s_n, 1);             // LDS atomic
        if (p < RCAP) { li[p] = fx - lo; lu[p] = uu; }
      }
    }
  }
  __syncthreads();
  int n = s_n; if (n > RCAP) n = RCAP;

  for (int cI = wid; cI < n; cI += 4) {         // one wave per candidate
    int j = li[cI];
    const float4* p  = reinterpret_cast<const float4*>(w + (size_t)j * D);
    const float4* qp = reinterpret_cast<const float4*>(q);
    float dot = 0.f, n2 = 0.f;
#pragma unroll
    for (int k = 0; k < 3; ++k) {
      float4 a = p[k * 64 + lane];
      float4 b = qp[k * 64 + lane];
      dot += a.x * b.x + a.y * b.y + a.z * b.z + a.w * b.w;
      n2  += a.x * a.x + a.y * a.y + a.z * a.z + a.w * a.w;
    }
#pragma unroll
    for (int off = 32; off > 0; off >>= 1) {
      dot += __shfl_down(dot, off, 64);
      n2  += __shfl_down(n2,  off, 64);
    }
    if (lane == 0) {
      float invj = 1.0f / fmaxf(sqrtf(n2), 1e-12f);
      lsc[cI] = invq * invj * dot + TWO_OVER_EPS * (-logf(-logf(lu[cI])));
    }
  }
  __syncthreads();

  if (wid == 0) {                               // argmax: (score desc, idx asc)
    float bs = -INFINITY;
    int bj = 0x7fffffff;
    for (int cI = lane; cI < n; cI += 64) {
      float s = lsc[cI];
      int j = li[cI];
      if (s > bs || (s == bs && j < bj)) { bs = s; bj = j; }
    }
#pragma unroll
    for (int off = 32; off > 0; off >>= 1) {
      float os = __shfl_down(bs, off, 64);
      int   oj = __shfl_down(bj, off, 64);
      if (os > bs || (os == bs && oj < bj)) { bs = os; bj = oj; }
    }
    if (lane == 0) s_sel = bj;
  }
  __syncthreads();

  int sel = s_sel;
#pragma unroll
  for (int k = 0; k < 3; ++k)
    out[(size_t)row * D + k * 256 + tid] = w[(size_t)sel * D + k * 256 + tid];
}

extern "C" void kernel_launch(void* const* d_in, const int* in_sizes, int n_in,
                              void* d_out, int out_size, void* d_ws, size_t ws_size,
                              hipStream_t stream) {
  const int*   ids = (const int*)d_in[0];    // input_ids (B*T)
  const float* w   = (const float*)d_in[1];  // weight (V*D)
  const float* gum = (const float*)d_in[2];  // gumbel_u (BT*V)
  float* out = (float*)d_out;

  // ws layout (all fields fully rewritten every call -> no zeroing needed)
  constexpr size_t O_CCNT = 0;
  constexpr size_t O_MLO  = O_CCNT + (size_t)NWC * 4;
  constexpr size_t O_MHI  = O_MLO  + (size_t)NWC * 4;
  constexpr size_t O_CFL  = O_MHI  + (size_t)NWC * 4;
  constexpr size_t O_CUV  = O_CFL  + (size_t)NWC * CCAP * 4;  // ~3.8 MB total
  char* ws = (char*)d_ws;
  int*   ccnt   = (int*)(ws + O_CCNT);
  float* cmaxlo = (float*)(ws + O_MLO);
  float* cmaxhi = (float*)(ws + O_MHI);
  int*   cflat  = (int*)(ws + O_CFL);
  float* cuv    = (float*)(ws + O_CUV);

  k_scan<<<(NWC + 3) / 4, 256, 0, stream>>>(gum, ccnt, cflat, cuv, cmaxlo, cmaxhi);
  k_score<<<BT, 256, 0, stream>>>(w, ids, ccnt, cflat, cuv, cmaxlo, cmaxhi, out);
}